// Round 8
// baseline (295.471 us; speedup 1.0000x reference)
//
#include <hip/hip_runtime.h>
#include <math.h>

#define Bq 4
#define Hh 16
#define Lq 1024
#define Dd 64
#define Kk 8
#define QT 128        // q rows per block (32 per wave, 4 waves)
#define KT 128        // k rows per iteration = 2 sub-tiles of 64
#define NSPLIT 2      // split-K factor (fixed-max softmax -> partials just add)
#define KSPAN (Lq / NSPLIT)
#define SRk 72        // K LDS row stride (bf16 elems)
#define SRv 136       // V^T LDS row stride (128 cols + pad)
#define TB 768        // bias table entries (single copy)
#define FMAX 8.0f     // fixed softmax shift (verified safe R1-R6)
#define LOG2E 1.44269504f

typedef __attribute__((ext_vector_type(8))) short short8;   // 8 bf16
typedef __attribute__((ext_vector_type(4))) short short4v;  // 4 bf16
typedef __attribute__((ext_vector_type(16))) float f32x16;

// fp32 -> bf16 round-half-up: 2 VALU ops, <=1 ulp vs RNE
__device__ __forceinline__ short f2bh(float x) {
    return (short)((__float_as_uint(x) + 0x8000u) >> 16);
}

// j-permutation (verified R4-R6): V row j -> column slot so the S^T C/D
// register layout IS the PV A-fragment layout (P never touches LDS).
__device__ __forceinline__ int jperm(int j) {
    return (j & 32) | ((j & 8) << 1) | ((j & 4) << 1) | ((j & 16) >> 2) | (j & 3);
}

// ---------------------------------------------------------------------------
// Kernel A: split-K flash attention partial. Grid (64 bh, 8 qtile, 2 split).
// Un-normalized O partial: split 0 -> d_out, split 1 -> ws (plain stores, NO
// atomics — R6 showed atomics cost 700 MB of HBM RMW traffic). Row sums -> ws.
// ---------------------------------------------------------------------------
__global__ __launch_bounds__(256, 4) void attn_kernel(
    const float* __restrict__ qp, const float* __restrict__ kp,
    const float* __restrict__ vp,
    const float* __restrict__ off, const float* __restrict__ amp,
    const float* __restrict__ sh, const float* __restrict__ bpar,
    float* __restrict__ out, float* __restrict__ part,
    float* __restrict__ l_ws)
{
    __shared__ __align__(16) short k_s[KT * SRk];   // 18432 B
    __shared__ __align__(16) short v_s[Dd * SRv];   // 17408 B
    __shared__ __align__(16) float bias_s[TB];      //  3072 B  (38.9 KB total)

    const int bh = blockIdx.x;            // fastest -> XCD = bh%8
    const int qt = blockIdx.y;
    const int z  = blockIdx.z;            // split index
    const int qs = qt * QT;
    const int koff = z * KSPAN;
    const int t  = threadIdx.x;
    const int w  = t >> 6;
    const int lane = t & 63;
    const int l31 = lane & 31;
    const int h5  = lane >> 5;
    const int h   = bh & 15;

    // ---- bias table: (log(ksum+eps+bp) - |rel|*slope - FMAX)*log2e ----
    float slope = (h < Hh - 2) ? 4.605170185988092f * exp2f(-6.0f * (float)h / 13.0f) : 0.0f;
    #pragma unroll
    for (int it = 0; it < 3; ++it) {
        int i = it * 256 + t;             // 0..767
        float rel = (float)(i - 127 + koff - qs);
        float ksum = 0.0f;
        #pragma unroll
        for (int kk = 0; kk < Kk; ++kk) {
            float a = amp[kk * Hh + h];
            float o = off[kk * Hh + h];
            float s = sh[kk * Hh + h];
            float sgn = (a > 0.0f) ? 1.0f : ((a < 0.0f) ? -1.0f : 0.0f);
            ksum += fabsf(a) / (1.0f + __expf(-sgn * (rel - o) / s));
        }
        bias_s[i] = (logf(ksum + 1e-8f + bpar[h]) - fabsf(rel) * slope - FMAX) * LOG2E;
    }

    // ---- Q B-frags (global, once), scale folded ----
    const float QS = 0.125f * LOG2E;
    short8 bq[4];
    const float* qrow = qp + ((size_t)bh * Lq + qs + 32 * w + l31) * Dd;
    #pragma unroll
    for (int c = 0; c < 4; ++c) {
        float4 x0 = *(const float4*)(qrow + c * 16 + h5 * 8);
        float4 x1 = *(const float4*)(qrow + c * 16 + h5 * 8 + 4);
        short8 a;
        a[0]=f2bh(x0.x*QS); a[1]=f2bh(x0.y*QS); a[2]=f2bh(x0.z*QS); a[3]=f2bh(x0.w*QS);
        a[4]=f2bh(x1.x*QS); a[5]=f2bh(x1.y*QS); a[6]=f2bh(x1.z*QS); a[7]=f2bh(x1.w*QS);
        bq[c] = a;
    }

    // ---- staging geometry: thread owns 4 consecutive rows x 4 cols per sub
    const int g  = t >> 4;
    const int cl = t & 15;
    const int j0 = 4 * g;
    const int c4 = 4 * cl;
    const int vcb[2] = { jperm(j0), 64 + jperm(j0) };
    const float* kbase = kp + ((size_t)bh * Lq + koff) * Dd;
    const float* vbase = vp + ((size_t)bh * Lq + koff) * Dd;

    // ---- prefetch iteration 0 ----
    float4 kr[2][4], vr[2][4];
    #pragma unroll
    for (int s = 0; s < 2; ++s)
        #pragma unroll
        for (int u = 0; u < 4; ++u) {
            kr[s][u] = *(const float4*)(kbase + (size_t)(64 * s + j0 + u) * Dd + c4);
            vr[s][u] = *(const float4*)(vbase + (size_t)(64 * s + j0 + u) * Dd + c4);
        }
    // ---- write tile 0 ----
    #pragma unroll
    for (int s = 0; s < 2; ++s) {
        #pragma unroll
        for (int u = 0; u < 4; ++u) {
            short4v k4;
            k4[0]=f2bh(kr[s][u].x); k4[1]=f2bh(kr[s][u].y);
            k4[2]=f2bh(kr[s][u].z); k4[3]=f2bh(kr[s][u].w);
            *(short4v*)&k_s[(64 * s + j0 + u) * SRk + c4] = k4;
        }
        #pragma unroll
        for (int cc = 0; cc < 4; ++cc) {
            int d = c4 + cc;
            short4v v4;
            v4[0]=f2bh(((const float*)&vr[s][0])[cc]);
            v4[1]=f2bh(((const float*)&vr[s][1])[cc]);
            v4[2]=f2bh(((const float*)&vr[s][2])[cc]);
            v4[3]=f2bh(((const float*)&vr[s][3])[cc]);
            *(short4v*)&v_s[d * SRv + (vcb[s] ^ (8 * ((d >> 3) & 7)))] = v4;
        }
    }
    __syncthreads();

    // ---- accumulators ----
    f32x16 O0, O1;
    #pragma unroll
    for (int r = 0; r < 16; ++r) { O0[r] = 0.f; O1[r] = 0.f; }
    float l_part = 0.0f;

    const int L0 = 4 * h5 - 32 * w - l31 + 127;   // bias lane offset

    #pragma unroll 1
    for (int kt = 0; kt < KSPAN / KT; ++kt) {     // 4 iterations
        const int ks = kt * KT;

        if (kt < KSPAN / KT - 1) {
            const float* kn = kbase + (size_t)(ks + KT) * Dd;
            const float* vn = vbase + (size_t)(ks + KT) * Dd;
            #pragma unroll
            for (int s = 0; s < 2; ++s)
                #pragma unroll
                for (int u = 0; u < 4; ++u) {
                    kr[s][u] = *(const float4*)(kn + (size_t)(64 * s + j0 + u) * Dd + c4);
                    vr[s][u] = *(const float4*)(vn + (size_t)(64 * s + j0 + u) * Dd + c4);
                }
        }

        #pragma unroll
        for (int s = 0; s < 2; ++s) {
            // ---- S^T = K Q^T ----
            f32x16 S0, S1;
            #pragma unroll
            for (int r = 0; r < 16; ++r) { S0[r] = 0.f; S1[r] = 0.f; }
            #pragma unroll
            for (int c = 0; c < 4; ++c) {
                short8 ak0 = *(const short8*)&k_s[(64 * s + l31) * SRk + c * 16 + h5 * 8];
                S0 = __builtin_amdgcn_mfma_f32_32x32x16_bf16(ak0, bq[c], S0, 0, 0, 0);
            }
            #pragma unroll
            for (int c = 0; c < 4; ++c) {
                short8 ak1 = *(const short8*)&k_s[(64 * s + 32 + l31) * SRk + c * 16 + h5 * 8];
                S1 = __builtin_amdgcn_mfma_f32_32x32x16_bf16(ak1, bq[c], S1, 0, 0, 0);
            }

            // ---- softmax: p = exp2(S + bias') ----
            float lsum = 0.0f;
            #pragma unroll
            for (int p = 0; p < 4; ++p) {
                int base0 = ks + 64 * s + 8 * p + L0;
                #pragma unroll
                for (int q = 0; q < 4; ++q) {
                    int r = 4 * p + q;
                    float e0 = __builtin_amdgcn_exp2f(S0[r] + bias_s[base0 + q]);
                    float e1 = __builtin_amdgcn_exp2f(S1[r] + bias_s[base0 + q + 32]);
                    S0[r] = e0; S1[r] = e1;
                    lsum += e0 + e1;
                }
            }
            l_part += lsum;

            // ---- P A-frags purely in-register (jperm trick) ----
            short8 ap[4];
            #pragma unroll
            for (int c = 0; c < 4; ++c) {
                short8 a;
                #pragma unroll
                for (int e = 0; e < 8; ++e) {
                    int r = (c & 1) * 4 + (e & 3) + 8 * (e >> 2);
                    a[e] = f2bh((c >> 1) ? S1[r] : S0[r]);
                }
                ap[c] = a;
            }

            // ---- O += P V ----
            #pragma unroll
            for (int nb = 0; nb < 2; ++nb) {
                int d = nb * 32 + l31;
                int swz = 8 * ((d >> 3) & 7);
                f32x16 acc = nb ? O1 : O0;
                #pragma unroll
                for (int c = 0; c < 4; ++c) {
                    short8 bv = *(const short8*)&v_s[d * SRv + 64 * s + ((c * 16 + h5 * 8) ^ swz)];
                    acc = __builtin_amdgcn_mfma_f32_32x32x16_bf16(ap[c], bv, acc, 0, 0, 0);
                }
                if (nb) O1 = acc; else O0 = acc;
            }
        }

        __syncthreads();
        if (kt < KSPAN / KT - 1) {
            #pragma unroll
            for (int s = 0; s < 2; ++s) {
                #pragma unroll
                for (int u = 0; u < 4; ++u) {
                    short4v k4;
                    k4[0]=f2bh(kr[s][u].x); k4[1]=f2bh(kr[s][u].y);
                    k4[2]=f2bh(kr[s][u].z); k4[3]=f2bh(kr[s][u].w);
                    *(short4v*)&k_s[(64 * s + j0 + u) * SRk + c4] = k4;
                }
                #pragma unroll
                for (int cc = 0; cc < 4; ++cc) {
                    int d = c4 + cc;
                    short4v v4;
                    v4[0]=f2bh(((const float*)&vr[s][0])[cc]);
                    v4[1]=f2bh(((const float*)&vr[s][1])[cc]);
                    v4[2]=f2bh(((const float*)&vr[s][2])[cc]);
                    v4[3]=f2bh(((const float*)&vr[s][3])[cc]);
                    *(short4v*)&v_s[d * SRv + (vcb[s] ^ (8 * ((d >> 3) & 7)))] = v4;
                }
            }
        }
        __syncthreads();
    }

    // ---- epilogue: l to ws; un-normalized O plain-stored per split ----
    float l = l_part;
    l += __shfl_xor(l, 32);               // merge the two j-halves
    if (h5 == 0)
        l_ws[(((size_t)z * 64 + bh) * 8 + qt) * QT + 32 * w + l31] = l;

    float* dst = (z == 0) ? out : part;
    float* ob = dst + ((size_t)bh * Lq + qs) * Dd;
    #pragma unroll
    for (int r = 0; r < 16; ++r) {
        int rowp = (r & 3) + 8 * (r >> 2) + 4 * h5;
        ob[(size_t)(32 * w + rowp) * Dd + l31]      = O0[r];
        ob[(size_t)(32 * w + rowp) * Dd + 32 + l31] = O1[r];
    }
}

// ---------------------------------------------------------------------------
// Kernel B: out = (out + part) / (l0 + l1).  float4 per thread.
// ---------------------------------------------------------------------------
__global__ __launch_bounds__(256) void comb_kernel(
    float* __restrict__ out, const float* __restrict__ part,
    const float* __restrict__ l_ws)
{
    int gid = blockIdx.x * 256 + threadIdx.x;       // float4 index, 1M total
    int rowg = gid >> 4;                            // global row 0..65535
    int bh = rowg >> 10;
    int rin = rowg & 1023;
    int qt = rin >> 7;
    int r  = rin & 127;
    size_t li = ((size_t)bh * 8 + qt) * QT + r;
    float l = l_ws[li] + l_ws[64 * 8 * QT + li];
    float inv = 1.0f / l;
    float4 o = ((float4*)out)[gid];
    float4 p = ((const float4*)part)[gid];
    o.x = (o.x + p.x) * inv;
    o.y = (o.y + p.y) * inv;
    o.z = (o.z + p.z) * inv;
    o.w = (o.w + p.w) * inv;
    ((float4*)out)[gid] = o;
}

extern "C" void kernel_launch(void* const* d_in, const int* in_sizes, int n_in,
                              void* d_out, int out_size, void* d_ws, size_t ws_size,
                              hipStream_t stream) {
    const float* q   = (const float*)d_in[0];
    const float* k   = (const float*)d_in[1];
    const float* v   = (const float*)d_in[2];
    const float* off = (const float*)d_in[3];
    const float* amp = (const float*)d_in[4];
    const float* sh  = (const float*)d_in[5];
    const float* bp  = (const float*)d_in[6];
    float* out  = (float*)d_out;
    float* l_ws = (float*)d_ws;                     // 131072 floats = 512 KB
    float* part = (float*)((char*)d_ws + 524288);   // 16 MB fp32 O-partial

    dim3 grid(Bq * Hh, Lq / QT, NSPLIT);  // (64, 8, 2), bh fastest
    attn_kernel<<<grid, 256, 0, stream>>>(q, k, v, off, amp, sh, bp,
                                          out, part, l_ws);

    comb_kernel<<<(Bq * Hh * Lq * Dd / 4) / 256, 256, 0, stream>>>(out, part, l_ws);
}

// Round 9
// 145.802 us; speedup vs baseline: 2.0265x; 2.0265x over previous
//
#include <hip/hip_runtime.h>
#include <math.h>

#define Bq 4
#define Hh 16
#define Lq 1024
#define Dd 64
#define Kk 8
#define QT 128        // q rows per block (32 per wave, 4 waves)
#define KT 128        // k rows per iteration = 2 sub-tiles of 64
#define NSPLIT 2      // split-K factor (fixed-max softmax -> partials just add)
#define KSPAN (Lq / NSPLIT)
#define SRk 72        // K LDS row stride (bf16 elems)
#define SRv 136       // V^T LDS row stride (128 cols + pad)
#define TB 768        // bias table entries (single copy)
#define FMAX 8.0f     // fixed softmax shift (verified safe R1-R7)
#define LOG2E 1.44269504f

typedef __attribute__((ext_vector_type(8))) short short8;   // 8 bf16
typedef __attribute__((ext_vector_type(4))) short short4v;  // 4 bf16
typedef __attribute__((ext_vector_type(16))) float f32x16;

// fp32 -> bf16 round-half-up: 2 VALU ops, <=1 ulp vs RNE
__device__ __forceinline__ short f2bh(float x) {
    return (short)((__float_as_uint(x) + 0x8000u) >> 16);
}

// j-permutation (verified R4-R7): V row j -> column slot so the S^T C/D
// register layout IS the PV A-fragment layout (P never touches LDS).
__device__ __forceinline__ int jperm(int j) {
    return (j & 32) | ((j & 8) << 1) | ((j & 4) << 1) | ((j & 16) >> 2) | (j & 3);
}

// ---------------------------------------------------------------------------
// Kernel A: split-K flash attention partial. Grid (64 bh, 8 qtile, 2 split).
// Un-normalized O partial: split 0 -> d_out, split 1 -> ws. Row sums -> ws.
// __launch_bounds__(256,2): R6/R7 post-mortem — (256,4) capped VGPR at 64 and
// the ~130-reg live set spilled ~700 MB of scratch traffic/launch (205 us).
// (256,2) -> 128 VGPRs, spill-free (proven R5); 4 blocks/CU comes from the
// 38.9 KB LDS footprint, not the launch-bounds arg.
// ---------------------------------------------------------------------------
__global__ __launch_bounds__(256, 2) void attn_kernel(
    const float* __restrict__ qp, const float* __restrict__ kp,
    const float* __restrict__ vp,
    const float* __restrict__ off, const float* __restrict__ amp,
    const float* __restrict__ sh, const float* __restrict__ bpar,
    float* __restrict__ out, float* __restrict__ part,
    float* __restrict__ l_ws)
{
    __shared__ __align__(16) short k_s[KT * SRk];   // 18432 B
    __shared__ __align__(16) short v_s[Dd * SRv];   // 17408 B
    __shared__ __align__(16) float bias_s[TB];      //  3072 B  (38.9 KB total)

    const int bh = blockIdx.x;            // fastest -> XCD = bh%8
    const int qt = blockIdx.y;
    const int z  = blockIdx.z;            // split index
    const int qs = qt * QT;
    const int koff = z * KSPAN;
    const int t  = threadIdx.x;
    const int w  = t >> 6;
    const int lane = t & 63;
    const int l31 = lane & 31;
    const int h5  = lane >> 5;
    const int h   = bh & 15;

    // ---- bias table: (log(ksum+eps+bp) - |rel|*slope - FMAX)*log2e ----
    float slope = (h < Hh - 2) ? 4.605170185988092f * exp2f(-6.0f * (float)h / 13.0f) : 0.0f;
    #pragma unroll
    for (int it = 0; it < 3; ++it) {
        int i = it * 256 + t;             // 0..767
        float rel = (float)(i - 127 + koff - qs);
        float ksum = 0.0f;
        #pragma unroll
        for (int kk = 0; kk < Kk; ++kk) {
            float a = amp[kk * Hh + h];
            float o = off[kk * Hh + h];
            float s = sh[kk * Hh + h];
            float sgn = (a > 0.0f) ? 1.0f : ((a < 0.0f) ? -1.0f : 0.0f);
            ksum += fabsf(a) / (1.0f + __expf(-sgn * (rel - o) / s));
        }
        bias_s[i] = (logf(ksum + 1e-8f + bpar[h]) - fabsf(rel) * slope - FMAX) * LOG2E;
    }

    // ---- Q B-frags (global, once), scale folded ----
    const float QS = 0.125f * LOG2E;
    short8 bq[4];
    const float* qrow = qp + ((size_t)bh * Lq + qs + 32 * w + l31) * Dd;
    #pragma unroll
    for (int c = 0; c < 4; ++c) {
        float4 x0 = *(const float4*)(qrow + c * 16 + h5 * 8);
        float4 x1 = *(const float4*)(qrow + c * 16 + h5 * 8 + 4);
        short8 a;
        a[0]=f2bh(x0.x*QS); a[1]=f2bh(x0.y*QS); a[2]=f2bh(x0.z*QS); a[3]=f2bh(x0.w*QS);
        a[4]=f2bh(x1.x*QS); a[5]=f2bh(x1.y*QS); a[6]=f2bh(x1.z*QS); a[7]=f2bh(x1.w*QS);
        bq[c] = a;
    }

    // ---- staging geometry: thread owns 4 consecutive rows x 4 cols per sub
    const int g  = t >> 4;
    const int cl = t & 15;
    const int j0 = 4 * g;
    const int c4 = 4 * cl;
    const int vcb[2] = { jperm(j0), 64 + jperm(j0) };
    const float* kbase = kp + ((size_t)bh * Lq + koff) * Dd;
    const float* vbase = vp + ((size_t)bh * Lq + koff) * Dd;

    // ---- prefetch iteration 0 ----
    float4 kr[2][4], vr[2][4];
    #pragma unroll
    for (int s = 0; s < 2; ++s)
        #pragma unroll
        for (int u = 0; u < 4; ++u) {
            kr[s][u] = *(const float4*)(kbase + (size_t)(64 * s + j0 + u) * Dd + c4);
            vr[s][u] = *(const float4*)(vbase + (size_t)(64 * s + j0 + u) * Dd + c4);
        }
    // ---- write tile 0 ----
    #pragma unroll
    for (int s = 0; s < 2; ++s) {
        #pragma unroll
        for (int u = 0; u < 4; ++u) {
            short4v k4;
            k4[0]=f2bh(kr[s][u].x); k4[1]=f2bh(kr[s][u].y);
            k4[2]=f2bh(kr[s][u].z); k4[3]=f2bh(kr[s][u].w);
            *(short4v*)&k_s[(64 * s + j0 + u) * SRk + c4] = k4;
        }
        #pragma unroll
        for (int cc = 0; cc < 4; ++cc) {
            int d = c4 + cc;
            short4v v4;
            v4[0]=f2bh(((const float*)&vr[s][0])[cc]);
            v4[1]=f2bh(((const float*)&vr[s][1])[cc]);
            v4[2]=f2bh(((const float*)&vr[s][2])[cc]);
            v4[3]=f2bh(((const float*)&vr[s][3])[cc]);
            *(short4v*)&v_s[d * SRv + (vcb[s] ^ (8 * ((d >> 3) & 7)))] = v4;
        }
    }
    __syncthreads();

    // ---- accumulators ----
    f32x16 O0, O1;
    #pragma unroll
    for (int r = 0; r < 16; ++r) { O0[r] = 0.f; O1[r] = 0.f; }
    float l_part = 0.0f;

    const int L0 = 4 * h5 - 32 * w - l31 + 127;   // bias lane offset

    #pragma unroll 1
    for (int kt = 0; kt < KSPAN / KT; ++kt) {     // 4 iterations
        const int ks = kt * KT;

        if (kt < KSPAN / KT - 1) {
            const float* kn = kbase + (size_t)(ks + KT) * Dd;
            const float* vn = vbase + (size_t)(ks + KT) * Dd;
            #pragma unroll
            for (int s = 0; s < 2; ++s)
                #pragma unroll
                for (int u = 0; u < 4; ++u) {
                    kr[s][u] = *(const float4*)(kn + (size_t)(64 * s + j0 + u) * Dd + c4);
                    vr[s][u] = *(const float4*)(vn + (size_t)(64 * s + j0 + u) * Dd + c4);
                }
        }

        #pragma unroll
        for (int s = 0; s < 2; ++s) {
            // ---- S^T = K Q^T ----
            f32x16 S0, S1;
            #pragma unroll
            for (int r = 0; r < 16; ++r) { S0[r] = 0.f; S1[r] = 0.f; }
            #pragma unroll
            for (int c = 0; c < 4; ++c) {
                short8 ak0 = *(const short8*)&k_s[(64 * s + l31) * SRk + c * 16 + h5 * 8];
                S0 = __builtin_amdgcn_mfma_f32_32x32x16_bf16(ak0, bq[c], S0, 0, 0, 0);
            }
            #pragma unroll
            for (int c = 0; c < 4; ++c) {
                short8 ak1 = *(const short8*)&k_s[(64 * s + 32 + l31) * SRk + c * 16 + h5 * 8];
                S1 = __builtin_amdgcn_mfma_f32_32x32x16_bf16(ak1, bq[c], S1, 0, 0, 0);
            }

            // ---- softmax: p = exp2(S + bias') ----
            float lsum = 0.0f;
            #pragma unroll
            for (int p = 0; p < 4; ++p) {
                int base0 = ks + 64 * s + 8 * p + L0;
                #pragma unroll
                for (int q = 0; q < 4; ++q) {
                    int r = 4 * p + q;
                    float e0 = __builtin_amdgcn_exp2f(S0[r] + bias_s[base0 + q]);
                    float e1 = __builtin_amdgcn_exp2f(S1[r] + bias_s[base0 + q + 32]);
                    S0[r] = e0; S1[r] = e1;
                    lsum += e0 + e1;
                }
            }
            l_part += lsum;

            // ---- P A-frags purely in-register (jperm trick) ----
            short8 ap[4];
            #pragma unroll
            for (int c = 0; c < 4; ++c) {
                short8 a;
                #pragma unroll
                for (int e = 0; e < 8; ++e) {
                    int r = (c & 1) * 4 + (e & 3) + 8 * (e >> 2);
                    a[e] = f2bh((c >> 1) ? S1[r] : S0[r]);
                }
                ap[c] = a;
            }

            // ---- O += P V ----
            #pragma unroll
            for (int nb = 0; nb < 2; ++nb) {
                int d = nb * 32 + l31;
                int swz = 8 * ((d >> 3) & 7);
                f32x16 acc = nb ? O1 : O0;
                #pragma unroll
                for (int c = 0; c < 4; ++c) {
                    short8 bv = *(const short8*)&v_s[d * SRv + 64 * s + ((c * 16 + h5 * 8) ^ swz)];
                    acc = __builtin_amdgcn_mfma_f32_32x32x16_bf16(ap[c], bv, acc, 0, 0, 0);
                }
                if (nb) O1 = acc; else O0 = acc;
            }
        }

        __syncthreads();
        if (kt < KSPAN / KT - 1) {
            #pragma unroll
            for (int s = 0; s < 2; ++s) {
                #pragma unroll
                for (int u = 0; u < 4; ++u) {
                    short4v k4;
                    k4[0]=f2bh(kr[s][u].x); k4[1]=f2bh(kr[s][u].y);
                    k4[2]=f2bh(kr[s][u].z); k4[3]=f2bh(kr[s][u].w);
                    *(short4v*)&k_s[(64 * s + j0 + u) * SRk + c4] = k4;
                }
                #pragma unroll
                for (int cc = 0; cc < 4; ++cc) {
                    int d = c4 + cc;
                    short4v v4;
                    v4[0]=f2bh(((const float*)&vr[s][0])[cc]);
                    v4[1]=f2bh(((const float*)&vr[s][1])[cc]);
                    v4[2]=f2bh(((const float*)&vr[s][2])[cc]);
                    v4[3]=f2bh(((const float*)&vr[s][3])[cc]);
                    *(short4v*)&v_s[d * SRv + (vcb[s] ^ (8 * ((d >> 3) & 7)))] = v4;
                }
            }
        }
        __syncthreads();
    }

    // ---- epilogue: l to ws; un-normalized O plain-stored per split ----
    float l = l_part;
    l += __shfl_xor(l, 32);               // merge the two j-halves
    if (h5 == 0)
        l_ws[(((size_t)z * 64 + bh) * 8 + qt) * QT + 32 * w + l31] = l;

    float* dst = (z == 0) ? out : part;
    float* ob = dst + ((size_t)bh * Lq + qs) * Dd;
    #pragma unroll
    for (int r = 0; r < 16; ++r) {
        int rowp = (r & 3) + 8 * (r >> 2) + 4 * h5;
        ob[(size_t)(32 * w + rowp) * Dd + l31]      = O0[r];
        ob[(size_t)(32 * w + rowp) * Dd + 32 + l31] = O1[r];
    }
}

// ---------------------------------------------------------------------------
// Kernel B: out = (out + part) / (l0 + l1).  float4 per thread.
// ---------------------------------------------------------------------------
__global__ __launch_bounds__(256) void comb_kernel(
    float* __restrict__ out, const float* __restrict__ part,
    const float* __restrict__ l_ws)
{
    int gid = blockIdx.x * 256 + threadIdx.x;       // float4 index, 1M total
    int rowg = gid >> 4;                            // global row 0..65535
    int bh = rowg >> 10;
    int rin = rowg & 1023;
    int qt = rin >> 7;
    int r  = rin & 127;
    size_t li = ((size_t)bh * 8 + qt) * QT + r;
    float l = l_ws[li] + l_ws[64 * 8 * QT + li];
    float inv = 1.0f / l;
    float4 o = ((float4*)out)[gid];
    float4 p = ((const float4*)part)[gid];
    o.x = (o.x + p.x) * inv;
    o.y = (o.y + p.y) * inv;
    o.z = (o.z + p.z) * inv;
    o.w = (o.w + p.w) * inv;
    ((float4*)out)[gid] = o;
}

extern "C" void kernel_launch(void* const* d_in, const int* in_sizes, int n_in,
                              void* d_out, int out_size, void* d_ws, size_t ws_size,
                              hipStream_t stream) {
    const float* q   = (const float*)d_in[0];
    const float* k   = (const float*)d_in[1];
    const float* v   = (const float*)d_in[2];
    const float* off = (const float*)d_in[3];
    const float* amp = (const float*)d_in[4];
    const float* sh  = (const float*)d_in[5];
    const float* bp  = (const float*)d_in[6];
    float* out  = (float*)d_out;
    float* l_ws = (float*)d_ws;                     // 131072 floats = 512 KB
    float* part = (float*)((char*)d_ws + 524288);   // 16 MB fp32 O-partial

    dim3 grid(Bq * Hh, Lq / QT, NSPLIT);  // (64, 8, 2), bh fastest
    attn_kernel<<<grid, 256, 0, stream>>>(q, k, v, off, amp, sh, bp,
                                          out, part, l_ws);

    comb_kernel<<<(Bq * Hh * Lq * Dd / 4) / 256, 256, 0, stream>>>(out, part, l_ws);
}